// Round 13
// baseline (1596.003 us; speedup 1.0000x reference)
//
#include <hip/hip_runtime.h>
#include <stdint.h>
#include <math.h>

typedef short short8 __attribute__((ext_vector_type(8)));
typedef float floatx4 __attribute__((ext_vector_type(4)));
typedef uint32_t uint4v __attribute__((ext_vector_type(4)));

#define MFMA(a, b, c) __builtin_amdgcn_mfma_f32_16x16x32_bf16((a), (b), (c), 0, 0, 0)

#define B_   64
#define S_   256
#define DIN  512
#define DH   1024
#define G3   3072
#define DOUT 64
#define M_   (B_ * S_)  // 16384
#define NBLK 128        // persistent blocks: 64 col-chunks x 2 batch halves

// bf16 negative-NaN pair. |h| < 1 always (tanh/sigmoid bounded) and f2bf of a
// finite float in (-1,1) can never produce 0xFFC0 -> impossible as real data.
#define POISON 0xFFC0FFC0u

#define AGENT_ST_U32(p, v) __hip_atomic_store((p), (v), __ATOMIC_RELAXED, __HIP_MEMORY_SCOPE_AGENT)

__device__ __forceinline__ unsigned short f2bf(float f) {
    union { float f; uint32_t u; } v; v.f = f;
    uint32_t u = v.u;
    uint32_t r = (u + 0x7fffu + ((u >> 16) & 1u)) >> 16;  // RNE
    return (unsigned short)r;
}
__device__ __forceinline__ float bf2f(unsigned short s) {
    union { uint32_t u; float f; } v; v.u = ((uint32_t)s) << 16; return v.f;
}
__device__ __forceinline__ short8 ld8(const unsigned short* p) {
    return *reinterpret_cast<const short8*>(p);
}
__device__ __forceinline__ float fast_sigmoid(float x) {
    return 1.f / (1.f + __expf(-x));
}
__device__ __forceinline__ float fast_tanh(float x) {
    return 1.f - 2.f / (__expf(2.f * x) + 1.f);
}

// Coherent tile-slice load: 8 x dwordx4 (16B/lane each) with L1+L2 bypass
// (sc0 sc1) so every retry observes the MALL -- the point producers' agent
// stores write through to. One vmcnt(0) for the batch; in-order retirement
// means a producer's own outstanding store-acks drain IN PARALLEL with these
// loads (overlapped, not additive). 13-bit imm offset covers the +2048B pair.
__device__ __forceinline__ void poll_tile8(
        const unsigned short* p0, const unsigned short* p1,
        const unsigned short* p2, const unsigned short* p3,
        short8& a0, short8& a1, short8& a2, short8& a3,
        short8& a4, short8& a5, short8& a6, short8& a7) {
    asm volatile(
        "global_load_dwordx4 %0, %8, off sc0 sc1\n\t"
        "global_load_dwordx4 %1, %8, off offset:2048 sc0 sc1\n\t"
        "global_load_dwordx4 %2, %9, off sc0 sc1\n\t"
        "global_load_dwordx4 %3, %9, off offset:2048 sc0 sc1\n\t"
        "global_load_dwordx4 %4, %10, off sc0 sc1\n\t"
        "global_load_dwordx4 %5, %10, off offset:2048 sc0 sc1\n\t"
        "global_load_dwordx4 %6, %11, off sc0 sc1\n\t"
        "global_load_dwordx4 %7, %11, off offset:2048 sc0 sc1\n\t"
        "s_waitcnt vmcnt(0)"
        : "=&v"(a0), "=&v"(a1), "=&v"(a2), "=&v"(a3),
          "=&v"(a4), "=&v"(a5), "=&v"(a6), "=&v"(a7)
        : "v"(p0), "v"(p1), "v"(p2), "v"(p3)
        : "memory");
}

// ---------------- elementwise: fp32 -> bf16 cast ----------------
__global__ void cast_bf16_kernel(const float* __restrict__ src,
                                 unsigned short* __restrict__ dst, int n) {
    int i = blockIdx.x * 256 + threadIdx.x;
    if (i < n) dst[i] = f2bf(src[i]);
}

// ---------------- poison the hs buffer (ws is 0xAA-poisoned, not poison-coded) ----
__global__ void poison_hs_kernel(uint4v* hs4) {
    size_t i = (size_t)blockIdx.x * 256 + threadIdx.x;
    size_t n = (size_t)M_ * DH / 8;
    uint4v pv = {POISON, POISON, POISON, POISON};
    if (i < n) hs4[i] = pv;
}

// ---------------- embedding gather into [s*64+b][512] bf16 ----------------
__global__ void gather_kernel(const int* __restrict__ x, const float* __restrict__ emb,
                              unsigned short* __restrict__ xe) {
    int g = blockIdx.x * 256 + threadIdx.x;  // 16384*512 total
    int m = g >> 9;          // row = s*64+b
    int k = g & 511;
    int s = m >> 6, b = m & 63;
    int tok = x[b * S_ + s];
    xe[(size_t)m * DIN + k] = f2bf(emb[(size_t)tok * DIN + k]);
}

// ---------------- bt-GEMM: C[M,N] bf16 = A[M,K] @ W[N,K]^T + bias ----------------
__global__ __launch_bounds__(256) void gemm_bt_bias(
        const unsigned short* __restrict__ A, const unsigned short* __restrict__ W,
        const float* __restrict__ bias, unsigned short* __restrict__ C,
        int M, int N, int K) {
    __shared__ __align__(16) unsigned short As[128 * 32];
    __shared__ __align__(16) unsigned short Ws[128 * 32];
    int tid = threadIdx.x;
    int lane = tid & 63, wv = tid >> 6;
    int wm = wv >> 1, wn = wv & 1;
    int q = lane >> 4, l15 = lane & 15;
    int bm = blockIdx.x, bn = blockIdx.y;

    floatx4 acc[4][4];
    floatx4 z = {0.f, 0.f, 0.f, 0.f};
    for (int i = 0; i < 4; i++) for (int j = 0; j < 4; j++) acc[i][j] = z;

    int row_s = tid >> 1;
    int col_s = (tid & 1) * 16;
    const unsigned short* Ab = A + (size_t)(bm * 128 + row_s) * K + col_s;
    const unsigned short* Wb = W + (size_t)(bn * 128 + row_s) * K + col_s;
    unsigned short* AsW = &As[row_s * 32 + col_s];
    unsigned short* WsW = &Ws[row_s * 32 + col_s];

    for (int k0 = 0; k0 < K; k0 += 32) {
        __syncthreads();
        *reinterpret_cast<short8*>(AsW)     = ld8(Ab + k0);
        *reinterpret_cast<short8*>(AsW + 8) = ld8(Ab + k0 + 8);
        *reinterpret_cast<short8*>(WsW)     = ld8(Wb + k0);
        *reinterpret_cast<short8*>(WsW + 8) = ld8(Wb + k0 + 8);
        __syncthreads();
        short8 af[4], wf[4];
        for (int t = 0; t < 4; t++) {
            af[t] = ld8(&As[(wm * 64 + t * 16 + l15) * 32 + q * 8]);
            wf[t] = ld8(&Ws[(wn * 64 + t * 16 + l15) * 32 + q * 8]);
        }
        for (int i = 0; i < 4; i++)
            for (int j = 0; j < 4; j++)
                acc[i][j] = MFMA(af[i], wf[j], acc[i][j]);
    }
    for (int i = 0; i < 4; i++) {
        int row = bm * 128 + wm * 64 + i * 16 + q * 4;
        for (int j = 0; j < 4; j++) {
            int col = bn * 128 + wn * 64 + j * 16 + l15;
            float bv = bias[col];
            for (int r = 0; r < 4; r++)
                C[(size_t)(row + r) * N + col] = f2bf(acc[i][j][r] + bv);
        }
    }
}

// ---------------- persistent GRU recurrence ----------------
// R12 skeleton (946us): tiled single-writer hs (R9), per-wave dependencies,
// one barrier/step, kh==1 loader waves own the gi prefetch (gil LDS handoff).
//
// ONE change this round: SENTINEL-IN-TILE sync. The measured step (~8.9K cy)
// vs the accounted chain (~3K) implies a per-hop MALL RT ~2K cy at this
// occupancy, i.e. the step is ~4 serial hops: drain + publish->detect +
// h-fetch + compute. Flags can't go below 3 hops. So: remove the flag
// protocol entirely. Producers fire their 4 tile stores and move on (no
// vmcnt drain, no publish). Consumers poll the DATA: hs is pre-poisoned with
// impossible bf16 NaN pairs; each wave re-issues its 8 coalesced bypass
// (sc0 sc1) tile loads until every dword is non-poison. Detection and data
// transfer are the SAME round-trip (~1.5-2 hops total).
//
// Why this is sound now and wasn't in R1: R9's 512B single-writer tiles mean
// every polled line has ONE producer (R1 polled 4-writer cross-XCD
// partial-merge lines); polls are 16B/lane dwordx4 (not R7's dword storm);
// retries are throttled. In-order vmcnt retirement makes the gate wave's own
// store-acks drain in parallel with its first poll (overlap, not serial).
// Per-dword atomicity: each u32 is one producer lane's packed store ->
// per-dword poison check is race-free. Bypass loads never allocate into L2,
// so no stale lines can be cached for other waves. Fresh per-step addresses.
// Liveness: consumers wait only on step s-1 data, produced unconditionally;
// agent stores always become MALL-visible -> termination guaranteed.
__global__ __launch_bounds__(512, 2) void gru_persistent(
        const unsigned short* __restrict__ gi,   // [256][64][3072] bf16 (incl b_ih)
        const unsigned short* __restrict__ whh,  // [3072][1024] bf16
        const float* __restrict__ b_hh,          // [3072]
        unsigned short* __restrict__ hs) {       // tiled [256][2][64][2][16][16], poisoned
    const int tid = threadIdx.x;
    const int lane = tid & 63, wv = tid >> 6;
    const int mt = wv & 1, kh = wv >> 1;         // kh 0..3
    const int q = lane >> 4, l15 = lane & 15;
    const int jc = blockIdx.x >> 1, mh = blockIdx.x & 1;
    const int j = jc * 16 + l15;                 // h-col 0..1023
    const int brow0 = mh * 32 + mt * 16;         // wave's 16 batch rows

    __shared__ float red[2][3][2][3][64][4];     // [s&1][kh-1][mt][g][lane][r] = 36 KB
    __shared__ float gil[2][2][3][4][64];        // [s&1][mt][g][r][lane] = 24 KB

    // ---- register-resident weight fragments: rows {j, 1024+j, 2048+j}, K quarter kh ----
    short8 wfrag[3][8];
#pragma unroll
    for (int g = 0; g < 3; g++)
#pragma unroll
        for (int kk = 0; kk < 8; kk++)
            wfrag[g][kk] = ld8(whh + (size_t)(g * 1024 + j) * DH + kh * 256 + kk * 32 + q * 8);

    float bhr = 0.f, bhz = 0.f, bhn = 0.f;
    float hreg[4];
    float gir[4], giz[4], gin[4];
    if (kh == 0) {
        bhr = b_hh[j]; bhz = b_hh[1024 + j]; bhn = b_hh[2048 + j];
#pragma unroll
        for (int r = 0; r < 4; r++) {
            hreg[r] = 0.f;
            int b = brow0 + q * 4 + r;           // s=0 gi values (prologue only)
            gir[r] = bf2f(gi[(size_t)b * G3 + j]);
            giz[r] = bf2f(gi[(size_t)b * G3 + 1024 + j]);
            gin[r] = bf2f(gi[(size_t)b * G3 + 2048 + j]);
        }
    }

    union Frag { short8 v[8]; uint32_t w[32]; };

    for (int s = 0; s < S_; s++) {
        const int pb = s & 1;

        // ---- loader waves (kh==1): issue gi loads for s+1 FIRST; their
        // in-order drain overlaps the data-poll wait below.
        unsigned short gld[3][4];
        if (kh == 1 && s + 1 < S_) {
            const unsigned short* gp = gi + (size_t)(s + 1) * B_ * G3;
#pragma unroll
            for (int g = 0; g < 3; g++)
#pragma unroll
                for (int r = 0; r < 4; r++)
                    gld[g][r] = gp[(size_t)(brow0 + q * 4 + r) * G3 + g * 1024 + j];
            asm volatile("" ::: "memory");  // pin issue order: gi loads precede poll
        }

        // ---- sentinel-poll my h(s-1) slice, then MFMA phase ----
        floatx4 zf = {0.f, 0.f, 0.f, 0.f};
        floatx4 acc[3] = {zf, zf, zf};
        if (s > 0) {
            // tiled read: rows mh*32+mt*16+l15; k = kh*256 + kk*32 + q*8 ->
            // source tile jc_k = kh*16 + kk*2 + (q>>1), 16B half (q&1).
            const unsigned short* hb =
                hs + ((size_t)((s - 1) * 2 + mh) * 64) * 512 + mt * 256
                   + l15 * 16 + (q & 1) * 8 + (size_t)(kh * 16 + (q >> 1)) * 512;
            Frag f;
            for (;;) {
                poll_tile8(hb, hb + 2048, hb + 4096, hb + 6144,
                           f.v[0], f.v[1], f.v[2], f.v[3],
                           f.v[4], f.v[5], f.v[6], f.v[7]);
                uint32_t ok = 1u;
#pragma unroll
                for (int t = 0; t < 32; t++) ok &= (uint32_t)(f.w[t] != POISON);
                if (__all(ok != 0u)) break;
                __builtin_amdgcn_s_sleep(1);
            }
#pragma unroll
            for (int kk = 0; kk < 8; kk++)
#pragma unroll
                for (int g = 0; g < 3; g++)
                    acc[g] = MFMA(f.v[kk], wfrag[g][kk], acc[g]);
        }

        // ---- cross-wave K reduction (vector LDS writes) ----
        if (kh > 0) {
#pragma unroll
            for (int g = 0; g < 3; g++)
                *reinterpret_cast<floatx4*>(&red[pb][kh - 1][mt][g][lane][0]) = acc[g];
        }
        // ---- loader waves: convert + stash gi(s+1) into the OTHER gil buffer
        if (kh == 1 && s + 1 < S_) {
#pragma unroll
            for (int g = 0; g < 3; g++)
#pragma unroll
                for (int r = 0; r < 4; r++)
                    gil[(s + 1) & 1][mt][g][r][lane] = bf2f(gld[g][r]);
        }
        // red+gil handoff: LDS writes visible, then the ONE barrier per step.
        asm volatile("s_waitcnt lgkmcnt(0)" ::: "memory");
        __builtin_amdgcn_s_barrier();
        asm volatile("" ::: "memory");

        if (kh == 0) {
            // ---- gate phase (the two kh==0 waves) ----
            if (s > 0) {
#pragma unroll
                for (int r = 0; r < 4; r++) {
                    gir[r] = gil[pb][mt][0][r][lane];
                    giz[r] = gil[pb][mt][1][r][lane];
                    gin[r] = gil[pb][mt][2][r][lane];
                }
            }
#pragma unroll
            for (int p = 0; p < 3; p++)
#pragma unroll
                for (int g = 0; g < 3; g++) {
                    floatx4 v = *reinterpret_cast<const floatx4*>(&red[pb][p][mt][g][lane][0]);
                    acc[g] += v;
                }
            // this wave's OWN 512B tile: [s][mh][jc][mt][16][16]
            uint32_t* ht = (uint32_t*)(hs +
                ((size_t)(s * 2 + mh) * 64 + jc) * 512 + mt * 256);
#pragma unroll
            for (int r = 0; r < 4; r++) {
                float rg = fast_sigmoid(gir[r] + acc[0][r] + bhr);
                float zg = fast_sigmoid(giz[r] + acc[1][r] + bhz);
                float ng = fast_tanh(gin[r] + rg * (acc[2][r] + bhn));
                float h = (1.f - zg) * ng + zg * hreg[r];
                hreg[r] = h;
                // pack bf16 pair across adjacent lanes (tile cols l15, l15+1)
                float hnb = __shfl_xor(h, 1);
                if ((l15 & 1) == 0) {
                    uint32_t pk = (uint32_t)f2bf(h) | ((uint32_t)f2bf(hnb) << 16);
                    // 4 store instrs fully cover the 4-line tile: single-writer
                    // lines, no cross-XCD merge. Fire-and-forget: consumers
                    // detect the data itself (no drain, no flag).
                    AGENT_ST_U32(&ht[(q * 4 + r) * 8 + (l15 >> 1)], pk);
                }
            }
        }
        // all waves fall straight into step s+1: self-timed on the data.
    }
}

// ---------------- FC + log_softmax, fused (tiled hs reader) ----------------
__global__ __launch_bounds__(256) void fc_logsoftmax(
        const unsigned short* __restrict__ hs,    // tiled: [256][2][64][2][16][16]
        const unsigned short* __restrict__ fcw,   // [64][1024] bf16
        const float* __restrict__ fcb,            // [64]
        float* __restrict__ out) {                // [B][S][64]
    int tid = threadIdx.x;
    int lane = tid & 63, mt = tid >> 6;
    int q = lane >> 4, l15 = lane & 15;
    int s = blockIdx.x;                          // rows s*64 .. s*64+63

    floatx4 acc[4];
    floatx4 z = {0.f, 0.f, 0.f, 0.f};
    for (int nt = 0; nt < 4; nt++) acc[nt] = z;

    // A row b = mt*16 + l15 -> half mh=b>>5, producer tile mtb=(b>>4)&1, row b&15
    int b = mt * 16 + l15;
    int mh = b >> 5, mtb = (b >> 4) & 1, r16 = b & 15;
    const unsigned short* Ab =
        hs + ((size_t)(s * 2 + mh) * 64) * 512 + mtb * 256
           + r16 * 16 + (q & 1) * 8;
    const int jq = (q >> 1) * 512;               // jc half-step from q
    const unsigned short* Wp = fcw + (size_t)l15 * DH + q * 8;
    for (int k0 = 0; k0 < DH; k0 += 32) {
        // k = k0 + q*8 (+0..7): source tile jc = (k0>>4) + (q>>1)
        short8 a = ld8(Ab + (k0 >> 4) * 512 + jq);
        for (int nt = 0; nt < 4; nt++)
            acc[nt] = MFMA(a, ld8(Wp + (size_t)nt * 16 * DH + k0), acc[nt]);
    }

    float bv[4];
    for (int nt = 0; nt < 4; nt++) bv[nt] = fcb[nt * 16 + l15];

    for (int r = 0; r < 4; r++) {
        float v[4];
        for (int nt = 0; nt < 4; nt++) v[nt] = acc[nt][r] + bv[nt];
        float m = fmaxf(fmaxf(v[0], v[1]), fmaxf(v[2], v[3]));
        for (int off = 1; off < 16; off <<= 1) m = fmaxf(m, __shfl_xor(m, off));
        float se = __expf(v[0] - m) + __expf(v[1] - m) + __expf(v[2] - m) + __expf(v[3] - m);
        for (int off = 1; off < 16; off <<= 1) se += __shfl_xor(se, off);
        float L = logf(se);
        int brow = mt * 16 + q * 4 + r;          // C-frag row = batch index
        float* op = out + (size_t)(brow * S_ + s) * DOUT;
        for (int nt = 0; nt < 4; nt++) op[nt * 16 + l15] = v[nt] - m - L;
    }
}

extern "C" void kernel_launch(void* const* d_in, const int* in_sizes, int n_in,
                              void* d_out, int out_size, void* d_ws, size_t ws_size,
                              hipStream_t stream) {
    const int*   x    = (const int*)d_in[0];
    const float* emb  = (const float*)d_in[1];
    const float* w_ih = (const float*)d_in[2];
    const float* w_hh = (const float*)d_in[3];
    const float* b_ih = (const float*)d_in[4];
    const float* b_hh = (const float*)d_in[5];
    const float* fc_w = (const float*)d_in[6];
    const float* fc_b = (const float*)d_in[7];
    float* out = (float*)d_out;

    char* p = (char*)d_ws;
    unsigned short* xe    = (unsigned short*)p; p += (size_t)M_ * DIN * 2;   // 16 MB
    unsigned short* gi    = (unsigned short*)p; p += (size_t)M_ * G3 * 2;    // 100.7 MB
    unsigned short* wih_b = (unsigned short*)p; p += (size_t)G3 * DIN * 2;   // 3 MB
    unsigned short* whh_b = (unsigned short*)p; p += (size_t)G3 * DH * 2;    // 6.3 MB
    unsigned short* fcw_b = (unsigned short*)p; p += (size_t)DOUT * DH * 2;  // 128 KB
    unsigned short* hs    = (unsigned short*)p; p += (size_t)M_ * DH * 2;    // 33.6 MB

    poison_hs_kernel<<<(M_ * DH / 8 + 255) / 256, 256, 0, stream>>>((uint4v*)hs);
    cast_bf16_kernel<<<(G3 * DIN + 255) / 256, 256, 0, stream>>>(w_ih, wih_b, G3 * DIN);
    cast_bf16_kernel<<<(G3 * DH + 255) / 256, 256, 0, stream>>>(w_hh, whh_b, G3 * DH);
    cast_bf16_kernel<<<(DOUT * DH + 255) / 256, 256, 0, stream>>>(fc_w, fcw_b, DOUT * DH);
    gather_kernel<<<(M_ * DIN) / 256, 256, 0, stream>>>(x, emb, xe);

    gemm_bt_bias<<<dim3(M_ / 128, G3 / 128), 256, 0, stream>>>(
        xe, wih_b, b_ih, gi, M_, G3, DIN);

    gru_persistent<<<NBLK, 512, 0, stream>>>(gi, whh_b, b_hh, hs);

    fc_logsoftmax<<<S_, 256, 0, stream>>>(hs, fcw_b, fc_b, out);
}

// Round 14
// 1163.231 us; speedup vs baseline: 1.3720x; 1.3720x over previous
//
#include <hip/hip_runtime.h>
#include <stdint.h>
#include <math.h>

typedef short short8 __attribute__((ext_vector_type(8)));
typedef float floatx4 __attribute__((ext_vector_type(4)));

#define MFMA(a, b, c) __builtin_amdgcn_mfma_f32_16x16x32_bf16((a), (b), (c), 0, 0, 0)

#define B_   64
#define S_   256
#define DIN  512
#define DH   1024
#define G3   3072
#define DOUT 64
#define M_   (B_ * S_)  // 16384
#define NBLK 128        // persistent blocks: 64 col-chunks x 2 batch halves
#define FPAD 16         // dwords per flag slot (64B): 128B line = 2 slots = ONE block
#define NFLAG (S_ * 2 * 128 * FPAD)  // padded [s][mh][jc*2+mt] ready flags (4MB)

#define AGENT_LD_U32(p) __hip_atomic_load((p), __ATOMIC_RELAXED, __HIP_MEMORY_SCOPE_AGENT)
#define AGENT_ST_U32(p, v) __hip_atomic_store((p), (v), __ATOMIC_RELAXED, __HIP_MEMORY_SCOPE_AGENT)

typedef __attribute__((address_space(1))) const void* gas_t;
typedef __attribute__((address_space(3))) void* las_t;

__device__ __forceinline__ unsigned short f2bf(float f) {
    union { float f; uint32_t u; } v; v.f = f;
    uint32_t u = v.u;
    uint32_t r = (u + 0x7fffu + ((u >> 16) & 1u)) >> 16;  // RNE
    return (unsigned short)r;
}
__device__ __forceinline__ float bf2f(unsigned short s) {
    union { uint32_t u; float f; } v; v.u = ((uint32_t)s) << 16; return v.f;
}
__device__ __forceinline__ short8 ld8(const unsigned short* p) {
    return *reinterpret_cast<const short8*>(p);
}
__device__ __forceinline__ float fast_sigmoid(float x) {
    return 1.f / (1.f + __expf(-x));
}
__device__ __forceinline__ float fast_tanh(float x) {
    return 1.f - 2.f / (__expf(2.f * x) + 1.f);
}

// ---------------- elementwise: fp32 -> bf16 cast ----------------
__global__ void cast_bf16_kernel(const float* __restrict__ src,
                                 unsigned short* __restrict__ dst, int n) {
    int i = blockIdx.x * 256 + threadIdx.x;
    if (i < n) dst[i] = f2bf(src[i]);
}

// ---------------- zero the flag region (ws is poisoned 0xAA!) ----------------
__global__ void init_flags_kernel(unsigned int* flags) {
    int i = blockIdx.x * 256 + threadIdx.x;
    if (i < NFLAG) flags[i] = 0u;
}

// ---------------- embedding gather into [s*64+b][512] bf16 ----------------
__global__ void gather_kernel(const int* __restrict__ x, const float* __restrict__ emb,
                              unsigned short* __restrict__ xe) {
    int g = blockIdx.x * 256 + threadIdx.x;  // 16384*512 total
    int m = g >> 9;          // row = s*64+b
    int k = g & 511;
    int s = m >> 6, b = m & 63;
    int tok = x[b * S_ + s];
    xe[(size_t)m * DIN + k] = f2bf(emb[(size_t)tok * DIN + k]);
}

// ---------------- bt-GEMM: C[M,N] bf16 = A[M,K] @ W[N,K]^T + bias ----------------
// m97-style staging: __builtin_amdgcn_global_load_lds width=16 (the compiler
// never auto-emits it -- Common-mistake #1; m93->m97 was +69%). LDS dest is
// wave-uniform base + lane*16B (linear); per-lane global source supplies the
// layout. Chunk c = 16 rows x 32 cols of the [128][32] tile = 1KB; lane i
// covers row i>>2, 16B slot i&3 -> LDS offset i*16B = row*64 + (i&3)*16. Wave
// wv stages chunks {2wv, 2wv+1} of A and W (4 instrs/wave/K-step).
__global__ __launch_bounds__(256) void gemm_bt_bias(
        const unsigned short* __restrict__ A, const unsigned short* __restrict__ W,
        const float* __restrict__ bias, unsigned short* __restrict__ C,
        int M, int N, int K) {
    __shared__ __align__(16) unsigned short As[128 * 32];
    __shared__ __align__(16) unsigned short Ws[128 * 32];
    int tid = threadIdx.x;
    int lane = tid & 63, wv = tid >> 6;
    int wm = wv >> 1, wn = wv & 1;
    int q = lane >> 4, l15 = lane & 15;
    int bm = blockIdx.x, bn = blockIdx.y;

    floatx4 acc[4][4];
    floatx4 z = {0.f, 0.f, 0.f, 0.f};
    for (int i = 0; i < 4; i++) for (int j = 0; j < 4; j++) acc[i][j] = z;

    // staging addresses: chunk c0 = 2*wv (rows 16*c0..16*c0+15), c1 = c0+1
    const int c0 = wv * 2;
    const int rowc = lane >> 2;          // row within chunk
    const int colc = (lane & 3) * 8;     // ushort col offset (16B granule)
    const unsigned short* gA0 = A + (size_t)(bm * 128 + c0 * 16 + rowc) * K + colc;
    const unsigned short* gA1 = gA0 + (size_t)16 * K;
    const unsigned short* gW0 = W + (size_t)(bn * 128 + c0 * 16 + rowc) * K + colc;
    const unsigned short* gW1 = gW0 + (size_t)16 * K;
    unsigned short* lA0 = &As[c0 * 512];         // 512 ushorts = 1KB per chunk
    unsigned short* lA1 = &As[(c0 + 1) * 512];
    unsigned short* lW0 = &Ws[c0 * 512];
    unsigned short* lW1 = &Ws[(c0 + 1) * 512];

    for (int k0 = 0; k0 < K; k0 += 32) {
        __syncthreads();  // previous iter's readers done before overwrite
        __builtin_amdgcn_global_load_lds((gas_t)(gA0 + k0), (las_t)lA0, 16, 0, 0);
        __builtin_amdgcn_global_load_lds((gas_t)(gA1 + k0), (las_t)lA1, 16, 0, 0);
        __builtin_amdgcn_global_load_lds((gas_t)(gW0 + k0), (las_t)lW0, 16, 0, 0);
        __builtin_amdgcn_global_load_lds((gas_t)(gW1 + k0), (las_t)lW1, 16, 0, 0);
        __syncthreads();  // vmcnt(0) drain + barrier: tiles resident
        short8 af[4], wf[4];
        for (int t = 0; t < 4; t++) {
            af[t] = ld8(&As[(wm * 64 + t * 16 + l15) * 32 + q * 8]);
            wf[t] = ld8(&Ws[(wn * 64 + t * 16 + l15) * 32 + q * 8]);
        }
        for (int i = 0; i < 4; i++)
            for (int j = 0; j < 4; j++)
                acc[i][j] = MFMA(af[i], wf[j], acc[i][j]);
    }
    for (int i = 0; i < 4; i++) {
        int row = bm * 128 + wm * 64 + i * 16 + q * 4;
        for (int j = 0; j < 4; j++) {
            int col = bn * 128 + wn * 64 + j * 16 + l15;
            float bv = bias[col];
            for (int r = 0; r < 4; r++)
                C[(size_t)(row + r) * N + col] = f2bf(acc[i][j][r] + bv);
        }
    }
}

// ---------------- persistent GRU recurrence (R11, best measured: 938us) ----------
// Tiled single-writer hs (R9: no cross-XCD partial-line h merges), padded
// single-writer flag slots (R10: one writer block per flag line), per-wave
// 16-producer flag wait (R11), one raw barrier per step for the red[] handoff,
// vmcnt(0) drain before publish, gate-wave gi prefetch after publish.
__global__ __launch_bounds__(512, 2) void gru_persistent(
        const unsigned short* __restrict__ gi,   // [256][64][3072] bf16 (incl b_ih)
        const unsigned short* __restrict__ whh,  // [3072][1024] bf16
        const float* __restrict__ b_hh,          // [3072]
        unsigned short* __restrict__ hs,         // tiled: [256][2][64][2][16][16] bf16
        unsigned int* flags) {                   // padded: [256][2][128][FPAD]
    const int tid = threadIdx.x;
    const int lane = tid & 63, wv = tid >> 6;
    const int mt = wv & 1, kh = wv >> 1;         // kh 0..3
    const int q = lane >> 4, l15 = lane & 15;
    const int jc = blockIdx.x >> 1, mh = blockIdx.x & 1;
    const int j = jc * 16 + l15;                 // h-col 0..1023
    const int brow0 = mh * 32 + mt * 16;         // wave's 16 batch rows

    __shared__ float red[2][3][2][3][64][4];     // [s&1][kh-1][mt][g][lane][r] = 36 KB

    // ---- register-resident weight fragments: rows {j, 1024+j, 2048+j}, K quarter kh ----
    short8 wfrag[3][8];
#pragma unroll
    for (int g = 0; g < 3; g++)
#pragma unroll
        for (int kk = 0; kk < 8; kk++)
            wfrag[g][kk] = ld8(whh + (size_t)(g * 1024 + j) * DH + kh * 256 + kk * 32 + q * 8);

    float bhr = 0.f, bhz = 0.f, bhn = 0.f;
    float hreg[4];
    float gir[4], giz[4], gin[4];
    if (kh == 0) {
        bhr = b_hh[j]; bhz = b_hh[1024 + j]; bhn = b_hh[2048 + j];
#pragma unroll
        for (int r = 0; r < 4; r++) {
            hreg[r] = 0.f;
            int b = brow0 + q * 4 + r;           // initial gi prefetch (s=0)
            gir[r] = bf2f(gi[(size_t)b * G3 + j]);
            giz[r] = bf2f(gi[(size_t)b * G3 + 1024 + j]);
            gin[r] = bf2f(gi[(size_t)b * G3 + 2048 + j]);
        }
    }

    // my 16 producer flag slots for K quarter kh: jc' = kh*16 + l15, own mt/mh.
    // 4 lanes share each address (broadcast) -> 16 distinct 64B slots, one RT.
    const unsigned int* fbase =
        flags + ((kh * 16 + l15) * 2 + mt) * FPAD + mh * 128 * FPAD;

    for (int s = 0; s < S_; s++) {
        const int pb = s & 1;
        // ---- wait for MY 16 producers of step s-1, then MFMA phase ----
        floatx4 zf = {0.f, 0.f, 0.f, 0.f};
        floatx4 acc[3] = {zf, zf, zf};
        if (s > 0) {
            const unsigned int* fp = fbase + (size_t)((s - 1) << 1) * 128 * FPAD;
            while (!__all(AGENT_LD_U32(fp) != 0u)) {
                __builtin_amdgcn_s_sleep(1);
            }
            asm volatile("" ::: "memory");

            // tiled read: A rows = mh*32 + mt*16 + l15; k = kh*256 + kk*32 + q*8
            // -> source tile jc_k = kh*16 + kk*2 + (q>>1), 16B half (q&1).
            const unsigned short* hb =
                hs + ((size_t)((s - 1) * 2 + mh) * 64) * 512 + mt * 256
                   + l15 * 16 + (q & 1) * 8;
            const int jbase = (kh * 16 + (q >> 1)) * 512;
#pragma unroll
            for (int kk = 0; kk < 8; kk++) {
                short8 a = ld8(hb + jbase + kk * 1024);  // kk*2 tiles = 1024 ushort
#pragma unroll
                for (int g = 0; g < 3; g++)
                    acc[g] = MFMA(a, wfrag[g][kk], acc[g]);
            }
        }

        // ---- cross-wave K reduction (vector LDS writes) ----
        if (kh > 0) {
#pragma unroll
            for (int g = 0; g < 3; g++)
                *reinterpret_cast<floatx4*>(&red[pb][kh - 1][mt][g][lane][0]) = acc[g];
        }
        // red handoff: LDS writes visible, then the ONE barrier per step.
        asm volatile("s_waitcnt lgkmcnt(0)" ::: "memory");
        __builtin_amdgcn_s_barrier();
        asm volatile("" ::: "memory");

        if (kh == 0) {
            // ---- gate phase (the two kh==0 waves) ----
#pragma unroll
            for (int p = 0; p < 3; p++)
#pragma unroll
                for (int g = 0; g < 3; g++) {
                    floatx4 v = *reinterpret_cast<const floatx4*>(&red[pb][p][mt][g][lane][0]);
                    acc[g] += v;
                }
            // this wave's OWN 512B tile: [s][mh][jc][mt][16][16]
            uint32_t* ht = (uint32_t*)(hs +
                ((size_t)(s * 2 + mh) * 64 + jc) * 512 + mt * 256);
#pragma unroll
            for (int r = 0; r < 4; r++) {
                float rg = fast_sigmoid(gir[r] + acc[0][r] + bhr);
                float zg = fast_sigmoid(giz[r] + acc[1][r] + bhz);
                float ng = fast_tanh(gin[r] + rg * (acc[2][r] + bhn));
                float h = (1.f - zg) * ng + zg * hreg[r];
                hreg[r] = h;
                // pack bf16 pair across adjacent lanes (tile cols l15, l15+1)
                float hnb = __shfl_xor(h, 1);
                if ((l15 & 1) == 0) {
                    uint32_t pk = (uint32_t)f2bf(h) | ((uint32_t)f2bf(hnb) << 16);
                    // tile row = q*4+r (stride 8 dwords), col pair l15>>1.
                    // 4 store instrs fully cover the 4-line tile: single-writer
                    // lines, no cross-XCD merge.
                    AGENT_ST_U32(&ht[(q * 4 + r) * 8 + (l15 >> 1)], pk);
                }
            }
            if (s + 1 < S_) {
                // own-wave drain: stores at coherence point once vmcnt==0.
                // Then publish this wave's flag (single-writer 64B slot).
                asm volatile("" ::: "memory");
                asm volatile("s_waitcnt vmcnt(0)" ::: "memory");
                if (lane == 0)
                    AGENT_ST_U32(&flags[(((s << 1) + mh) * 128 + jc * 2 + mt) * FPAD], 1u);
                // gi prefetch for s+1 AFTER publish: HBM latency off the chain
                const unsigned short* gp = gi + (size_t)(s + 1) * B_ * G3;
#pragma unroll
                for (int r = 0; r < 4; r++) {
                    int b = brow0 + q * 4 + r;
                    gir[r] = bf2f(gp[(size_t)b * G3 + j]);
                    giz[r] = bf2f(gp[(size_t)b * G3 + 1024 + j]);
                    gin[r] = bf2f(gp[(size_t)b * G3 + 2048 + j]);
                }
            }
        }
        // kh>0 waves fall straight into step s+1: they self-time on their own
        // 16 producer flags (no release barrier needed).
    }
}

// ---------------- FC + log_softmax, fused (tiled hs reader) ----------------
__global__ __launch_bounds__(256) void fc_logsoftmax(
        const unsigned short* __restrict__ hs,    // tiled: [256][2][64][2][16][16]
        const unsigned short* __restrict__ fcw,   // [64][1024] bf16
        const float* __restrict__ fcb,            // [64]
        float* __restrict__ out) {                // [B][S][64]
    int tid = threadIdx.x;
    int lane = tid & 63, mt = tid >> 6;
    int q = lane >> 4, l15 = lane & 15;
    int s = blockIdx.x;                          // rows s*64 .. s*64+63

    floatx4 acc[4];
    floatx4 z = {0.f, 0.f, 0.f, 0.f};
    for (int nt = 0; nt < 4; nt++) acc[nt] = z;

    // A row b = mt*16 + l15 -> half mh=b>>5, producer tile mtb=(b>>4)&1, row b&15
    int b = mt * 16 + l15;
    int mh = b >> 5, mtb = (b >> 4) & 1, r16 = b & 15;
    const unsigned short* Ab =
        hs + ((size_t)(s * 2 + mh) * 64) * 512 + mtb * 256
           + r16 * 16 + (q & 1) * 8;
    const int jq = (q >> 1) * 512;               // jc half-step from q
    const unsigned short* Wp = fcw + (size_t)l15 * DH + q * 8;
    for (int k0 = 0; k0 < DH; k0 += 32) {
        // k = k0 + q*8 (+0..7): source tile jc = (k0>>4) + (q>>1)
        short8 a = ld8(Ab + (k0 >> 4) * 512 + jq);
        for (int nt = 0; nt < 4; nt++)
            acc[nt] = MFMA(a, ld8(Wp + (size_t)nt * 16 * DH + k0), acc[nt]);
    }

    float bv[4];
    for (int nt = 0; nt < 4; nt++) bv[nt] = fcb[nt * 16 + l15];

    for (int r = 0; r < 4; r++) {
        float v[4];
        for (int nt = 0; nt < 4; nt++) v[nt] = acc[nt][r] + bv[nt];
        float m = fmaxf(fmaxf(v[0], v[1]), fmaxf(v[2], v[3]));
        for (int off = 1; off < 16; off <<= 1) m = fmaxf(m, __shfl_xor(m, off));
        float se = __expf(v[0] - m) + __expf(v[1] - m) + __expf(v[2] - m) + __expf(v[3] - m);
        for (int off = 1; off < 16; off <<= 1) se += __shfl_xor(se, off);
        float L = logf(se);
        int brow = mt * 16 + q * 4 + r;          // C-frag row = batch index
        float* op = out + (size_t)(brow * S_ + s) * DOUT;
        for (int nt = 0; nt < 4; nt++) op[nt * 16 + l15] = v[nt] - m - L;
    }
}

extern "C" void kernel_launch(void* const* d_in, const int* in_sizes, int n_in,
                              void* d_out, int out_size, void* d_ws, size_t ws_size,
                              hipStream_t stream) {
    const int*   x    = (const int*)d_in[0];
    const float* emb  = (const float*)d_in[1];
    const float* w_ih = (const float*)d_in[2];
    const float* w_hh = (const float*)d_in[3];
    const float* b_ih = (const float*)d_in[4];
    const float* b_hh = (const float*)d_in[5];
    const float* fc_w = (const float*)d_in[6];
    const float* fc_b = (const float*)d_in[7];
    float* out = (float*)d_out;

    char* p = (char*)d_ws;
    unsigned int*   flags = (unsigned int*)p;   p += (size_t)NFLAG * 4;      // 4 MB
    unsigned short* xe    = (unsigned short*)p; p += (size_t)M_ * DIN * 2;   // 16 MB
    unsigned short* gi    = (unsigned short*)p; p += (size_t)M_ * G3 * 2;    // 100.7 MB
    unsigned short* wih_b = (unsigned short*)p; p += (size_t)G3 * DIN * 2;   // 3 MB
    unsigned short* whh_b = (unsigned short*)p; p += (size_t)G3 * DH * 2;    // 6.3 MB
    unsigned short* fcw_b = (unsigned short*)p; p += (size_t)DOUT * DH * 2;  // 128 KB
    unsigned short* hs    = (unsigned short*)p; p += (size_t)M_ * DH * 2;    // 33.6 MB

    init_flags_kernel<<<(NFLAG + 255) / 256, 256, 0, stream>>>(flags);
    cast_bf16_kernel<<<(G3 * DIN + 255) / 256, 256, 0, stream>>>(w_ih, wih_b, G3 * DIN);
    cast_bf16_kernel<<<(G3 * DH + 255) / 256, 256, 0, stream>>>(w_hh, whh_b, G3 * DH);
    cast_bf16_kernel<<<(DOUT * DH + 255) / 256, 256, 0, stream>>>(fc_w, fcw_b, DOUT * DH);
    gather_kernel<<<(M_ * DIN) / 256, 256, 0, stream>>>(x, emb, xe);

    gemm_bt_bias<<<dim3(M_ / 128, G3 / 128), 256, 0, stream>>>(
        xe, wih_b, b_ih, gi, M_, G3, DIN);

    gru_persistent<<<NBLK, 512, 0, stream>>>(gi, whh_b, b_hh, hs, flags);

    fc_logsoftmax<<<S_, 256, 0, stream>>>(hs, fcw_b, fc_b, out);
}